// Round 1
// 297.957 us; speedup vs baseline: 1.0824x; 1.0824x over previous
//
#include <hip/hip_runtime.h>
#include <stdint.h>

#define HASH_BUCKETS 1000
#define EMB_DIM 16
#define HDIM 32
#define G4 128   // 4*HDIM
#define TSTEPS 512
#define BATCH 4096

typedef short v8s __attribute__((ext_vector_type(8)));   // 8 bf16 (4 VGPRs)
typedef float v4f __attribute__((ext_vector_type(4)));   // MFMA acc

__device__ __forceinline__ float frcp(float x) {
    float r; asm("v_rcp_f32 %0, %1" : "=v"(r) : "v"(x)); return r;
}
__device__ __forceinline__ float fexp2(float x) {
    float r; asm("v_exp_f32 %0, %1" : "=v"(r) : "v"(x)); return r;
}
// packed f32->bf16 (RNE): dst.lo16 = bf16(lo), dst.hi16 = bf16(hi)
__device__ __forceinline__ uint32_t cvtpk_bf16(float lo, float hi) {
    uint32_t r; asm("v_cvt_pk_bf16_f32 %0, %1, %2" : "=v"(r) : "v"(lo), "v"(hi)); return r;
}
// f32 -> bf16 (RNE), bits in low 16 (used only in once-per-launch A-build)
__device__ __forceinline__ uint32_t bf16rne(float x) {
    uint32_t u = __float_as_uint(x);
    return (u + 0x7FFFu + ((u >> 16) & 1u)) >> 16;
}

// ---------------------------------------------------------------------------
// Kernel 1: embedding folded through input projection (r12 layout), now with
// the gate exp2-scaling folded in:  i/f/o rows x (-log2 e), c-row x (+2 log2 e).
// P2[bucket][h][g] = s_g * sum_e emb[bucket][e] * kernel[e][g*32 + h]
// ---------------------------------------------------------------------------
__global__ void precompute_P2_kernel(const float* __restrict__ emb,
                                     const float* __restrict__ kern,
                                     float* __restrict__ P2) {
    int idx = blockIdx.x * blockDim.x + threadIdx.x;
    if (idx >= HASH_BUCKETS * G4) return;
    int row = idx >> 7;
    int c2  = idx & 127;
    int h = c2 >> 2;
    int g = c2 & 3;
    float acc = 0.f;
#pragma unroll
    for (int e = 0; e < EMB_DIM; ++e)
        acc = fmaf(emb[row * EMB_DIM + e], kern[e * G4 + g * 32 + h], acc);
    float sg = (g == 2) ? 2.8853900817779268f : -1.4426950408889634f;
    P2[idx] = acc * sg;
}

// ---------------------------------------------------------------------------
// Kernel 2: r12 champion structure (4 waves = 16 batch, grid 256, distance-2
// xz prefetch) with chain-shortening changes this round:
//  (a) gate pre-scaling folded into P2 and A fragments; c kept in the
//      PL2E-scaled domain -> the two on-chain muls by +-log2e are gone.
//  (b) fmin clamps removed (|z'| ~ 3 on this data; c'/tanh paths are
//      NaN-free even at inf: rcp(inf)=0 -> tc=+-1, the correct limit).
//  (c) 3 INDEPENDENT MFMAs + add-tree instead of the dependent s0a->s0b
//      pair: chain depth 1 MFMA + 2 v4f adds instead of 2 MFMAs.
//  (d) h pack via v_cvt_pk_bf16_f32: depth-4 (cvt/and/sub/cvt) instead of
//      ~11-level double bf16rne. Precision identical (hi=RNE(h), lo=RNE(h-hi)).
//  (e) single ds_write_b64 per lane instead of 2 scattered b32: within each
//      8-slot block, phys = 2*quad + (k>=4); the A fragment is built in the
//      same permuted k-order (k = quad*8 + r + 4*e), so the MFMA dot product
//      is unchanged. Reader (2x b128 + perms) untouched.
//  (f) raw "s_waitcnt lgkmcnt(0); s_barrier" instead of __syncthreads():
//      no vmcnt(0) drain -> xz prefetch loads live across barriers.
//  (g) loop unrolled x2 so both double-buffer address sets are loop-invariant.
// ---------------------------------------------------------------------------
__global__ __launch_bounds__(256)
__attribute__((amdgpu_waves_per_eu(1, 1)))
void lstm_head_kernel(const int* __restrict__ ids,
                      const float* __restrict__ P2,   // [1000][32][4], pre-scaled
                      const float* __restrict__ R,    // rec_kernel [32][128]
                      const float* __restrict__ w1,   // [32][32]
                      const float* __restrict__ b1,   // [32]
                      const float* __restrict__ w2,   // [32]
                      const float* __restrict__ b2,   // [1]
                      float* __restrict__ out) {
    __shared__ __align__(16) uint32_t hbuf[2][16][36];
    __shared__ float hfin[16][33];

    const int tid  = threadIdx.x;
    const int w    = tid >> 6;        // wave 0..3
    const int lane = tid & 63;
    const int col  = lane & 15;       // batch within group
    const int quad = lane >> 4;       // 0..3
    const int bb   = blockIdx.x * 16;
    const int h0   = 8 * w + quad;
    const int h1   = h0 + 4;
    const int sw   = col & 3;         // bank swizzle key

    const float PL2E   =  2.8853900817779268f;   // 2*log2(e)
    const float N2PL2E = -5.7707801635558536f;   // -2*PL2E

    // ---- A fragments, pre-scaled by gate, in the b64-publish k-order ----
    union V8 { uint32_t u[4]; v8s v; };
    V8 A0hi, A0lo, A1hi, A1lo;
    {
        int tt = col >> 2, g = col & 3;
        float sg = (g == 2) ? PL2E : -1.4426950408889634f;
        int gc0 = g * 32 + 8 * w + tt;
        int gc1 = gc0 + 4;
#pragma unroll
        for (int r = 0; r < 4; ++r) {
            uint32_t h0p[2], l0p[2], h1p[2], l1p[2];
#pragma unroll
            for (int e = 0; e < 2; ++e) {
                // phys dword (2r+e) within an 8-block holds k = quad*8 + r + 4*e
                int k = quad * 8 + r + 4 * e;
                float x0 = R[k * G4 + gc0] * sg;
                uint32_t hb0 = bf16rne(x0);
                h0p[e] = hb0;
                l0p[e] = bf16rne(x0 - __uint_as_float(hb0 << 16));
                float x1 = R[k * G4 + gc1] * sg;
                uint32_t hb1 = bf16rne(x1);
                h1p[e] = hb1;
                l1p[e] = bf16rne(x1 - __uint_as_float(hb1 << 16));
            }
            A0hi.u[r] = h0p[0] | (h0p[1] << 16);
            A0lo.u[r] = l0p[0] | (l0p[1] << 16);
            A1hi.u[r] = h1p[0] | (h1p[1] << 16);
            A1lo.u[r] = l1p[0] | (l1p[1] << 16);
        }
    }

    for (int i = tid; i < 2 * 16 * 36; i += 256)
        ((uint32_t*)hbuf)[i] = 0u;

    // ---- deep prefetch pipeline (distance 2, r12-proven) ----
    const int* __restrict__ idrow = ids + (size_t)(bb + col) * TSTEPS;
    int ida = idrow[0];
    float4 xz0_c = *(const float4*)(P2 + (size_t)ida * G4 + 4 * h0);
    float4 xz1_c = *(const float4*)(P2 + (size_t)ida * G4 + 4 * h1);
    int idb = idrow[1];
    float4 xz0_n = *(const float4*)(P2 + (size_t)idb * G4 + 4 * h0);
    float4 xz1_n = *(const float4*)(P2 + (size_t)idb * G4 + 4 * h1);
    int id_c = idrow[2];
    int id_n = idrow[3];

    float c0 = 0.f, c1 = 0.f, hv0 = 0.f, hv1 = 0.f;
    const v4f vzero = {0.f, 0.f, 0.f, 0.f};

    // loop-invariant double-buffer addresses
    const uint32_t* rdp[2] = { &hbuf[0][col][8 * (quad ^ sw)],
                               &hbuf[1][col][8 * (quad ^ sw)] };
    uint32_t* wrp[2] = { &hbuf[1][col][8 * (w ^ sw) + 2 * quad],
                         &hbuf[0][col][8 * (w ^ sw) + 2 * quad] };

    __syncthreads();

#define STEP(PB, T)                                                             \
    {                                                                           \
        /* B fragment first: start LDS latency as early as possible */          \
        uint4 dA = *(const uint4*)(rdp[PB]);                                    \
        uint4 dB = *(const uint4*)(rdp[PB] + 4);                                \
        /* issue xz[t+2]; loads persist across raw barriers now */              \
        float4 xz0_f = *(const float4*)(P2 + (size_t)id_c * G4 + 4 * h0);       \
        float4 xz1_f = *(const float4*)(P2 + (size_t)id_c * G4 + 4 * h1);       \
        int id_f = idrow[((T) + 4 < TSTEPS) ? ((T) + 4) : (TSTEPS - 1)];        \
        V8 Bhi, Blo;                                                            \
        Bhi.u[0] = __builtin_amdgcn_perm(dA.y, dA.x, 0x07060302u);              \
        Bhi.u[1] = __builtin_amdgcn_perm(dA.w, dA.z, 0x07060302u);              \
        Bhi.u[2] = __builtin_amdgcn_perm(dB.y, dB.x, 0x07060302u);              \
        Bhi.u[3] = __builtin_amdgcn_perm(dB.w, dB.z, 0x07060302u);              \
        Blo.u[0] = __builtin_amdgcn_perm(dA.y, dA.x, 0x05040100u);              \
        Blo.u[1] = __builtin_amdgcn_perm(dA.w, dA.z, 0x05040100u);              \
        Blo.u[2] = __builtin_amdgcn_perm(dB.y, dB.x, 0x05040100u);              \
        Blo.u[3] = __builtin_amdgcn_perm(dB.w, dB.z, 0x05040100u);              \
        v4f xzv0 = {xz0_c.x, xz0_c.y, xz0_c.z, xz0_c.w};                        \
        v4f xzv1 = {xz1_c.x, xz1_c.y, xz1_c.z, xz1_c.w};                        \
        /* 3 independent MFMAs per z-group, add-tree after (lo*lo dropped) */   \
        v4f m0a = __builtin_amdgcn_mfma_f32_16x16x32_bf16(A0lo.v, Bhi.v, vzero, 0, 0, 0); \
        v4f m0b = __builtin_amdgcn_mfma_f32_16x16x32_bf16(A0hi.v, Blo.v, vzero, 0, 0, 0); \
        v4f m0c = __builtin_amdgcn_mfma_f32_16x16x32_bf16(A0hi.v, Bhi.v, xzv0, 0, 0, 0);  \
        v4f m1a = __builtin_amdgcn_mfma_f32_16x16x32_bf16(A1lo.v, Bhi.v, vzero, 0, 0, 0); \
        v4f m1b = __builtin_amdgcn_mfma_f32_16x16x32_bf16(A1hi.v, Blo.v, vzero, 0, 0, 0); \
        v4f m1c = __builtin_amdgcn_mfma_f32_16x16x32_bf16(A1hi.v, Bhi.v, xzv1, 0, 0, 0);  \
        v4f z0 = (m0a + m0b) + m0c;                                             \
        v4f z1 = (m1a + m1b) + m1c;                                             \
        /* z is pre-scaled: exp2 directly (no mul, no clamp) */                 \
        float di0 = 1.f + fexp2(z0[0]);                                         \
        float df0 = 1.f + fexp2(z0[1]);                                         \
        float dc0 = 1.f + fexp2(z0[2]);                                         \
        float dq0 = 1.f + fexp2(z0[3]);                                         \
        float di1 = 1.f + fexp2(z1[0]);                                         \
        float df1 = 1.f + fexp2(z1[1]);                                         \
        float dc1 = 1.f + fexp2(z1[2]);                                         \
        float dq1 = 1.f + fexp2(z1[3]);                                         \
        float Pp0 = di0 * df0, Qq0 = dc0 * dq0;                                 \
        float Pp1 = di1 * df1, Qq1 = dc1 * dq1;                                 \
        float rr0 = frcp(Pp0 * Qq0);                                            \
        float rr1 = frcp(Pp1 * Qq1);                                            \
        float rP0 = rr0 * Qq0, rQ0 = rr0 * Pp0;                                 \
        float rP1 = rr1 * Qq1, rQ1 = rr1 * Pp1;                                 \
        float ig0 = rP0 * df0, fg0 = rP0 * di0, rc0 = rQ0 * dq0, og0 = rQ0 * dc0; \
        float ig1 = rP1 * df1, fg1 = rP1 * di1, rc1 = rQ1 * dq1, og1 = rQ1 * dc1; \
        float tz0 = fmaf(N2PL2E, rc0, PL2E);  /* PL2E*tanh(zc) */               \
        float tz1 = fmaf(N2PL2E, rc1, PL2E);                                    \
        c0 = fmaf(fg0, c0, ig0 * tz0);        /* c kept in PL2E-scaled domain */\
        c1 = fmaf(fg1, c1, ig1 * tz1);                                          \
        float tc0 = fmaf(-2.f, frcp(1.f + fexp2(c0)), 1.f);                     \
        float tc1 = fmaf(-2.f, frcp(1.f + fexp2(c1)), 1.f);                     \
        hv0 = og0 * tc0;                                                        \
        hv1 = og1 * tc1;                                                        \
        /* split-bf16 pack via cvt_pk: hi=RNE(h), lo=RNE(h-hi), depth 4 */      \
        uint32_t t0 = cvtpk_bf16(hv0, hv0);                                     \
        float lo0 = hv0 - __uint_as_float(t0 & 0xffff0000u);                    \
        uint32_t pk0 = cvtpk_bf16(lo0, hv0);                                    \
        uint32_t t1 = cvtpk_bf16(hv1, hv1);                                     \
        float lo1 = hv1 - __uint_as_float(t1 & 0xffff0000u);                    \
        uint32_t pk1 = cvtpk_bf16(lo1, hv1);                                    \
        uint2 wv; wv.x = pk0; wv.y = pk1;                                       \
        *(uint2*)(wrp[PB]) = wv;   /* single b64 publish: k=8w+quad, 8w+4+quad */\
        xz0_c = xz0_n; xz1_c = xz1_n;                                           \
        xz0_n = xz0_f; xz1_n = xz1_f;                                           \
        id_c = id_n; id_n = id_f;                                               \
        /* raw barrier: LDS drain only, no vmcnt(0) */                          \
        asm volatile("s_waitcnt lgkmcnt(0)\n\ts_barrier" ::: "memory");         \
    }

    for (int t = 0; t < TSTEPS; t += 2) {
        STEP(0, t)
        STEP(1, t + 1)
    }
#undef STEP

    // ---- MLP head ----
    hfin[col][h0] = hv0;
    hfin[col][h1] = hv1;
    __syncthreads();

    int u = tid & 31;
    for (int bq = tid >> 5; bq < 16; bq += 8) {
        float y = b1[u];
#pragma unroll
        for (int k = 0; k < HDIM; ++k)
            y = fmaf(hfin[bq][k], w1[k * HDIM + u], y);
        y = fmaxf(y, 0.f);
        float vv = y * w2[u];
#pragma unroll
        for (int off = 16; off >= 1; off >>= 1)
            vv += __shfl_xor(vv, off);
        if (u == 0) out[bb + bq] = vv + b2[0];
    }
}

extern "C" void kernel_launch(void* const* d_in, const int* in_sizes, int n_in,
                              void* d_out, int out_size, void* d_ws, size_t ws_size,
                              hipStream_t stream) {
    const int*   ids  = (const int*)d_in[0];
    const float* emb  = (const float*)d_in[1];
    const float* kern = (const float*)d_in[2];
    const float* rec  = (const float*)d_in[3];
    const float* w1   = (const float*)d_in[4];
    const float* b1   = (const float*)d_in[5];
    const float* w2   = (const float*)d_in[6];
    const float* b2   = (const float*)d_in[7];
    float* out = (float*)d_out;
    float* P2  = (float*)d_ws;   // 512 KB scratch

    precompute_P2_kernel<<<(HASH_BUCKETS * G4 + 255) / 256, 256, 0, stream>>>(
        emb, kern, P2);
    lstm_head_kernel<<<BATCH / 16, 256, 0, stream>>>(
        ids, P2, rec, w1, b1, w2, b2, out);
}